// Round 13
// baseline (217.586 us; speedup 1.0000x reference)
//
#include <hip/hip_runtime.h>
#include <hip/hip_bf16.h>
#include <math.h>

#define ICH   3
#define OCH   16
#define ID    18
#define IH    34
#define IW    34
#define OD    16
#define OH    32
#define OW    32
#define NB    128
#define SPATIAL  (OD * OH * OW)     // 16384 per (b,c)
#define EPSV     1e-5f

typedef __attribute__((ext_vector_type(8))) short bf16x8;
typedef __attribute__((ext_vector_type(4))) float f32x4;

__device__ __forceinline__ unsigned int f2bf(float f) {
    unsigned int u = __float_as_uint(f);
    return (u + 0x7fffu + ((u >> 16) & 1u)) >> 16;
}

// ===== conv v6: MFMA im2col. The fp32 vector path has a hard 34.6 us FMA
// floor (5.44 GFLOP / 157 TF); R12 sat at 83 us. Move the MACs to the matrix
// pipe: GEMM C[16 oc][pos] = W[16 oc][96k] x im2col[96k][pos], 16x16x32 bf16
// MFMA (K=81 padded to 96, 3 MFMAs/tile).
// Block = 256 thr, tile = 1 (b,d) x 4h x 32w = 128 pos = 8 n-tiles. Grid 16384.
// Layouts (HW-verified, learn_hip): C/D col=lane&15(n=pos), row=quad*4+r(oc);
// A[m=lane&15][k=quad*8+j]; B[k=quad*8+j][n=lane&15]. k = ic*27+kd*9+kh*3+kw
// identically in A-frags and im2col build.
// LDS: xs 7.8KB (x subtile fp32) + Bb 24.5KB (im2col bf16, fragment order:
// b128 reads are a contiguous 1KB/wave, conflict-free) ~ 33KB -> 4 blocks/CU.
// y stored POSITION-MAJOR (lane writes 8B, wave writes 512B contiguous).
// Do NOT: raise min-waves (R2/R3 spill), runtime k-indices in build (R3:
// breaks compile-time folding), fp32-path tuning (35us floor).
__global__ __launch_bounds__(256) void conv_mfma_kernel(
    const float* __restrict__ x, const float* __restrict__ cw,
    const float* __restrict__ cb, const float* __restrict__ mult,
    unsigned short* __restrict__ y, float* __restrict__ stats)
{
    __shared__ float xs[3 * 3 * 6 * 36];                  // 7776 B
    __shared__ __align__(16) unsigned short Bb[12288];    // 24576 B
    __shared__ float wsum[4][OCH], wsq[4][OCH];

    const int blk  = blockIdx.x;
    const int b    = blk >> 7;
    const int rest = blk & 127;
    const int d    = rest >> 3;
    const int h0   = (rest & 7) << 2;
    const int tid  = threadIdx.x;
    const int lane = tid & 63;
    const int wid  = tid >> 6;
    const int quad = lane >> 4;
    const int ln   = lane & 15;

    // ---- stage x subtile: 3ic x 3kd x 6 rows x 34 cols (fp32) ----
    for (int i = tid; i < 3 * 3 * 6 * 34; i += 256) {
        const int col = i % 34;
        int r1 = i / 34;
        const int row = r1 % 6; r1 /= 6;
        const int kd = r1 % 3;
        const int ic = r1 / 3;
        xs[((ic * 3 + kd) * 6 + row) * 36 + col] =
            x[((size_t)(b * 3 + ic) * ID + d + kd) * (IH * IW)
              + (size_t)(h0 + row) * IW + col];
    }

    // ---- A fragments (weights, bf16): lane holds W[oc=ln][k=t*32+quad*8+j] ----
    bf16x8 afrag[3];
#pragma unroll
    for (int t = 0; t < 3; t++) {
        union { unsigned int u[4]; bf16x8 v; } au;
#pragma unroll
        for (int jp = 0; jp < 4; jp++) {
            const int k0 = t * 32 + quad * 8 + jp * 2;
            const unsigned int lo = (k0     < 81) ? f2bf(cw[ln * 81 + k0])     : 0u;
            const unsigned int hi = (k0 + 1 < 81) ? f2bf(cw[ln * 81 + k0 + 1]) : 0u;
            au.u[jp] = lo | (hi << 16);
        }
        afrag[t] = au.v;
    }

    __syncthreads();

    // ---- build im2col B in fragment order (all k compile-time) ----
    const int pos   = tid & 127;
    const int khalf = tid >> 7;          // wave-uniform (waves 0-1 vs 2-3)
    const int xsb   = (pos >> 5) * 36 + (pos & 31);          // + bh*36 + bw
    const int bwb   = (pos >> 4) * 1536 + (pos & 15) * 8;    // ushort index

    auto build2 = [&](const int k) {
        const int r0 = k % 27;
        const int o0 = (((k / 27) * 3 + r0 / 9) * 6 + (r0 % 9) / 3) * 36 + (r0 % 3);
        const int k1 = k + 1;
        const int r1 = k1 % 27;
        const int o1 = (((k1 / 27) * 3 + r1 / 9) * 6 + (r1 % 9) / 3) * 36 + (r1 % 3);
        const unsigned int lo = (k  < 81) ? f2bf(xs[xsb + o0]) : 0u;
        const unsigned int hi = (k1 < 81) ? f2bf(xs[xsb + o1]) : 0u;
        *(unsigned int*)&Bb[bwb + (k >> 5) * 512 + ((k >> 3) & 3) * 128 + (k & 7)]
            = lo | (hi << 16);
    };
    if (khalf == 0) {
#pragma unroll
        for (int kk = 0; kk < 48; kk += 2) build2(kk);
    } else {
#pragma unroll
        for (int kk = 48; kk < 96; kk += 2) build2(kk);
    }
    __syncthreads();

    // ---- MFMA: each wave does 2 n-tiles; fold bias+mult; pos-major y store ----
    float cbv[4], mv[4];
#pragma unroll
    for (int r = 0; r < 4; r++) { cbv[r] = cb[quad * 4 + r]; mv[r] = mult[quad * 4 + r]; }

    float ssum[4] = {0, 0, 0, 0}, ssq[4] = {0, 0, 0, 0};

#pragma unroll
    for (int it = 0; it < 2; it++) {
        const int nt = wid * 2 + it;
        f32x4 acc = {0.f, 0.f, 0.f, 0.f};
#pragma unroll
        for (int t = 0; t < 3; t++) {
            const bf16x8 bfrag =
                *(const bf16x8*)&Bb[nt * 1536 + t * 512 + quad * 128 + ln * 8];
            acc = __builtin_amdgcn_mfma_f32_16x16x32_bf16(afrag[t], bfrag, acc, 0, 0, 0);
        }
        const int hh = nt >> 1, ww = (nt & 1) * 16 + ln;
        float o[4];
#pragma unroll
        for (int r = 0; r < 4; r++) {
            o[r] = (acc[r] + cbv[r]) * mv[r];
            ssum[r] += o[r];
            ssq[r]  += o[r] * o[r];
        }
        const size_t posg = (((size_t)b * OD + d) * OH + (h0 + hh)) * OW + ww;
        uint2 pk;
        pk.x = f2bf(o[0]) | (f2bf(o[1]) << 16);
        pk.y = f2bf(o[2]) | (f2bf(o[3]) << 16);
        *(uint2*)&y[posg * 16 + quad * 4] = pk;
    }

    // ---- stats: reduce over the 16 n-lanes per quad, then cross-wave + atomic ----
#pragma unroll
    for (int r = 0; r < 4; r++) {
#pragma unroll
        for (int off = 8; off > 0; off >>= 1) {
            ssum[r] += __shfl_down(ssum[r], off, 16);
            ssq[r]  += __shfl_down(ssq[r], off, 16);
        }
    }
    if (ln == 0) {
#pragma unroll
        for (int r = 0; r < 4; r++) {
            wsum[wid][quad * 4 + r] = ssum[r];
            wsq[wid][quad * 4 + r]  = ssq[r];
        }
    }
    __syncthreads();
    if (tid < OCH) {
        float s = 0.0f, q = 0.0f;
#pragma unroll
        for (int k = 0; k < 4; k++) { s += wsum[k][tid]; q += wsq[k][tid]; }
        atomicAdd(&stats[(b * OCH + tid) * 2 + 0], s);
        atomicAdd(&stats[(b * OCH + tid) * 2 + 1], q);
    }
}

// ===== norm_max: R7's position-major streaming version (verified correct with
// pos-major y). Each thread: 8 positions x 32B contiguous; wave streams 16KB.
__global__ __launch_bounds__(256) void norm_max_kernel(
    const unsigned short* __restrict__ y, const float* __restrict__ stats,
    const float* __restrict__ mult, float* __restrict__ out)
{
    const int blk = blockIdx.x;
    const int b   = blk >> 3;
    const int seg = blk & 7;
    const int tid = threadIdx.x;

    __shared__ float srs_s[OCH], snb_s[OCH], smul_s[OCH];
    if (tid < OCH) {
        const float s  = stats[(b * OCH + tid) * 2 + 0];
        const float sq = stats[(b * OCH + tid) * 2 + 1];
        const float mean = s * (1.0f / (float)SPATIAL);
        float var = sq * (1.0f / (float)SPATIAL) - mean * mean;
        var = fmaxf(var, 0.0f);
        const float rs = rsqrtf(var + EPSV);
        srs_s[tid]  = rs;
        snb_s[tid]  = -mean * rs;      // normalized = v*rs + nb
        smul_s[tid] = mult[tid];
    }
    __syncthreads();

    float rs[OCH], nb[OCH], mm[OCH];
#pragma unroll
    for (int c = 0; c < OCH; c++) { rs[c] = srs_s[c]; nb[c] = snb_s[c]; mm[c] = smul_s[c]; }

    const size_t p0 = (size_t)b * SPATIAL + seg * 2048 + tid * 8;
    const uint4* src = (const uint4*)(y + p0 * OCH);

    float res[8];
#pragma unroll
    for (int half = 0; half < 2; half++) {
        uint4 v[8];
#pragma unroll
        for (int i = 0; i < 8; i++) v[i] = src[half * 8 + i];
#pragma unroll
        for (int j = 0; j < 4; j++) {
            const unsigned int uu[8] = {
                v[2 * j].x, v[2 * j].y, v[2 * j].z, v[2 * j].w,
                v[2 * j + 1].x, v[2 * j + 1].y, v[2 * j + 1].z, v[2 * j + 1].w };
            float best = -INFINITY;
#pragma unroll
            for (int k = 0; k < 8; k++) {
                float f0 = __uint_as_float(uu[k] << 16)         * rs[2 * k]     + nb[2 * k];
                float f1 = __uint_as_float(uu[k] & 0xffff0000u) * rs[2 * k + 1] + nb[2 * k + 1];
                f0 = fminf(fmaxf(f0, -1.0f), 1.0f) * mm[2 * k];
                f1 = fminf(fmaxf(f1, -1.0f), 1.0f) * mm[2 * k + 1];
                best = fmaxf(best, fmaxf(f0, f1));
            }
            res[half * 4 + j] = best;
        }
    }

    float* op = out + p0;
    float4 o0; o0.x = res[0]; o0.y = res[1]; o0.z = res[2]; o0.w = res[3];
    float4 o1; o1.x = res[4]; o1.y = res[5]; o1.z = res[6]; o1.w = res[7];
    *(float4*)op = o0;
    *(float4*)(op + 4) = o1;
}

extern "C" void kernel_launch(void* const* d_in, const int* in_sizes, int n_in,
                              void* d_out, int out_size, void* d_ws, size_t ws_size,
                              hipStream_t stream) {
    const float* x    = (const float*)d_in[0];
    const float* cw   = (const float*)d_in[1];
    const float* cb   = (const float*)d_in[2];
    const float* mult = (const float*)d_in[3];
    float* out = (float*)d_out;

    unsigned short* y = (unsigned short*)d_ws;   // position-major, 64 MB
    float* stats = (float*)((char*)d_ws + (size_t)NB * OCH * SPATIAL * sizeof(unsigned short));

    hipMemsetAsync(stats, 0, (size_t)NB * OCH * 2 * sizeof(float), stream);
    conv_mfma_kernel<<<NB * OD * 8, 256, 0, stream>>>(x, cw, cb, mult, y, stats);
    norm_max_kernel<<<NB * 8, 256, 0, stream>>>(y, stats, mult, out);
}

// Round 15
// 162.340 us; speedup vs baseline: 1.3403x; 1.3403x over previous
//
#include <hip/hip_runtime.h>
#include <hip/hip_bf16.h>
#include <math.h>

#define ICH   3
#define OCH   16
#define ID    18
#define IH    34
#define IW    34
#define OD    16
#define OH    32
#define OW    32
#define NB    128
#define SPATIAL  (OD * OH * OW)     // 16384 per (b,c)
#define EPSV     1e-5f

typedef __fp16 fp16x2 __attribute__((ext_vector_type(2)));

// ===== conv v7: R12's proven structure (83 us: direct-from-global, 1 d-slice
// per block, grid 2048, all-16-oc unroll, uniform weight idx -> s_load), with
// two epilogue cuts:
//  (1) y stored fp16 via v_cvt_pkrtz (1 instr/pair vs ~10 for bf16-rne pair):
//      kills the biggest non-FMA VALU block (~256 ops/thread -> ~40).
//  (2) per-block partial stats (no atomics, no memset dispatch): block (b,d)
//      writes wsum/wsq to stats[(b*OD+d)*OCH+c]; norm sums 16 partials.
// Do NOT: raise min-waves (R2/R3 spill), LDS-stage x (R1-R8), MFMA im2col
// (R13: marshaling >= the FMAs it replaces at M=16), fp16 staging of x (R5),
// grid caps/fusion (R11), smaller per-thread FMA volume (R8).
__global__ __launch_bounds__(256, 2) void conv_stats_kernel(
    const float* __restrict__ x, const float* __restrict__ cw,
    const float* __restrict__ cb, const float* __restrict__ mult,
    unsigned short* __restrict__ y, float* __restrict__ stats)
{
    __shared__ float wsum[4][OCH], wsq[4][OCH];

    const int blk = blockIdx.x;
    const int b = blk >> 4;
    const int d = blk & 15;
    const int tid = threadIdx.x;

    const int h  = tid >> 3;        // 0..31
    const int wq = (tid & 7) << 2;  // 0,4,...,28

    float acc[OCH][4];
#pragma unroll
    for (int c = 0; c < OCH; c++) {
        const float bv = cb[c];
        acc[c][0] = bv; acc[c][1] = bv; acc[c][2] = bv; acc[c][3] = bv;
    }

    for (int ic = 0; ic < ICH; ic++) {
        for (int kd = 0; kd < 3; kd++) {
            const float* plane = x + ((size_t)(b * ICH + ic) * ID + (d + kd)) * (IH * IW);
#pragma unroll
            for (int kh = 0; kh < 3; kh++) {
                const float* row = plane + (size_t)(h + kh) * IW + wq;
                const float4 v0 = *(const float4*)row;
                const float2 v1 = *(const float2*)(row + 4);
                float in[6];
                in[0] = v0.x; in[1] = v0.y; in[2] = v0.z; in[3] = v0.w;
                in[4] = v1.x; in[5] = v1.y;
                const float* wrow = &cw[(size_t)(ic * 3 + kd) * 9 + kh * 3];
#pragma unroll
                for (int kw = 0; kw < 3; kw++) {
#pragma unroll
                    for (int c = 0; c < OCH; c++) {
                        const float wv = wrow[(size_t)c * (ICH * 27) + kw];  // s_load
                        acc[c][0] = fmaf(in[kw + 0], wv, acc[c][0]);
                        acc[c][1] = fmaf(in[kw + 1], wv, acc[c][1]);
                        acc[c][2] = fmaf(in[kw + 2], wv, acc[c][2]);
                        acc[c][3] = fmaf(in[kw + 3], wv, acc[c][3]);
                    }
                }
            }
        }
    }

    // ---- multiplier fold, stats, fp16 store (v_cvt_pkrtz) ----
    float ssum[OCH], ssq[OCH];
#pragma unroll
    for (int c = 0; c < OCH; c++) {
        const float m = mult[c];
        const float o0 = acc[c][0] * m, o1 = acc[c][1] * m;
        const float o2 = acc[c][2] * m, o3 = acc[c][3] * m;
        ssum[c] = (o0 + o1) + (o2 + o3);
        ssq[c]  = (o0 * o0 + o1 * o1) + (o2 * o2 + o3 * o3);
        const size_t yi = ((size_t)(b * OCH + c) * OD + d) * (OH * OW) + h * OW + wq;
        union { fp16x2 h; unsigned int u; } p01, p23;
        p01.h = __builtin_amdgcn_cvt_pkrtz(o0, o1);
        p23.h = __builtin_amdgcn_cvt_pkrtz(o2, o3);
        uint2 pk; pk.x = p01.u; pk.y = p23.u;
        *(uint2*)&y[yi] = pk;
    }

    // ---- block reduction of stats, per-block partial write (no atomics) ----
#pragma unroll
    for (int c = 0; c < OCH; c++) {
        for (int off = 32; off > 0; off >>= 1) {
            ssum[c] += __shfl_down(ssum[c], off);
            ssq[c]  += __shfl_down(ssq[c], off);
        }
    }
    const int wave = tid >> 6, lane = tid & 63;
    if (lane == 0) {
#pragma unroll
        for (int c = 0; c < OCH; c++) { wsum[wave][c] = ssum[c]; wsq[wave][c] = ssq[c]; }
    }
    __syncthreads();
    if (tid < OCH) {
        float s = 0.0f, q = 0.0f;
#pragma unroll
        for (int k = 0; k < 4; k++) { s += wsum[k][tid]; q += wsq[k][tid]; }
        const int sbase = ((b * OD + d) * OCH + tid) * 2;
        stats[sbase + 0] = s;
        stats[sbase + 1] = q;
    }
}

// ===== norm_max (R12 structure). Prologue sums the 16 per-d partials
// (written non-atomically by conv; visible across the dispatch boundary).
// 2048 blocks, 4 positions/thread, all 16 channel loads hoisted.
__global__ __launch_bounds__(256, 2) void norm_max_kernel(
    const unsigned short* __restrict__ y, const float* __restrict__ stats,
    const float* __restrict__ mult, float* __restrict__ out)
{
    const int blk = blockIdx.x;
    const int b   = blk >> 4;
    const int seg = blk & 15;
    const int tid = threadIdx.x;

    __shared__ float srs_s[OCH], snb_s[OCH], smul_s[OCH];
    if (tid < OCH) {
        float s = 0.0f, q = 0.0f;
        for (int dd = 0; dd < OD; dd++) {
            s += stats[((b * OD + dd) * OCH + tid) * 2 + 0];
            q += stats[((b * OD + dd) * OCH + tid) * 2 + 1];
        }
        const float mean = s * (1.0f / (float)SPATIAL);
        float var = q * (1.0f / (float)SPATIAL) - mean * mean;
        var = fmaxf(var, 0.0f);
        const float rs = rsqrtf(var + EPSV);
        srs_s[tid]  = rs;
        snb_s[tid]  = -mean * rs;      // normalized = v*rs + nb
        smul_s[tid] = mult[tid];
    }
    __syncthreads();

    const int s = seg * 1024 + tid * 4;
    const unsigned short* yb = y + (size_t)b * OCH * SPATIAL + s;

    uint2 v[OCH];
#pragma unroll
    for (int c = 0; c < OCH; c++) {
        v[c] = *(const uint2*)(yb + (size_t)c * SPATIAL);
    }

    float rs[OCH], nb[OCH], mm[OCH];
#pragma unroll
    for (int c = 0; c < OCH; c++) { rs[c] = srs_s[c]; nb[c] = snb_s[c]; mm[c] = smul_s[c]; }

    float b0 = -INFINITY, b1 = -INFINITY, b2 = -INFINITY, b3 = -INFINITY;
#pragma unroll
    for (int c = 0; c < OCH; c++) {
        union { unsigned int u; __fp16 h[2]; } a0, a1;
        a0.u = v[c].x; a1.u = v[c].y;
        float f0 = (float)a0.h[0] * rs[c] + nb[c];
        float f1 = (float)a0.h[1] * rs[c] + nb[c];
        float f2 = (float)a1.h[0] * rs[c] + nb[c];
        float f3 = (float)a1.h[1] * rs[c] + nb[c];
        f0 = fminf(fmaxf(f0, -1.0f), 1.0f) * mm[c];
        f1 = fminf(fmaxf(f1, -1.0f), 1.0f) * mm[c];
        f2 = fminf(fmaxf(f2, -1.0f), 1.0f) * mm[c];
        f3 = fminf(fmaxf(f3, -1.0f), 1.0f) * mm[c];
        b0 = fmaxf(b0, f0); b1 = fmaxf(b1, f1);
        b2 = fmaxf(b2, f2); b3 = fmaxf(b3, f3);
    }
    float4 o; o.x = b0; o.y = b1; o.z = b2; o.w = b3;
    *(float4*)&out[(size_t)b * SPATIAL + s] = o;
}

extern "C" void kernel_launch(void* const* d_in, const int* in_sizes, int n_in,
                              void* d_out, int out_size, void* d_ws, size_t ws_size,
                              hipStream_t stream) {
    const float* x    = (const float*)d_in[0];
    const float* cw   = (const float*)d_in[1];
    const float* cb   = (const float*)d_in[2];
    const float* mult = (const float*)d_in[3];
    float* out = (float*)d_out;

    // ws: y (fp16, 64 MB) | stats partials (128*16*16*2 f32 = 256 KB)
    unsigned short* y = (unsigned short*)d_ws;
    float* stats = (float*)((char*)d_ws + (size_t)NB * OCH * SPATIAL * sizeof(unsigned short));

    conv_stats_kernel<<<NB * 16, 256, 0, stream>>>(x, cw, cb, mult, y, stats);
    norm_max_kernel<<<NB * 16, 256, 0, stream>>>(y, stats, mult, out);
}

// Round 16
// 147.572 us; speedup vs baseline: 1.4744x; 1.1001x over previous
//
#include <hip/hip_runtime.h>
#include <hip/hip_bf16.h>
#include <math.h>

#define ICH   3
#define OCH   16
#define ID    18
#define IH    34
#define IW    34
#define OD    16
#define OH    32
#define OW    32
#define NB    128
#define SPATIAL  (OD * OH * OW)     // 16384 per (b,c)
#define EPSV     1e-5f

typedef __fp16 fp16x2 __attribute__((ext_vector_type(2)));

// Tiny pre-pass: transpose weights [oc][k=81] -> [k=81][oc=16] so the conv's
// per-(ic,kd,kh) weight group (48 floats) is CONTIGUOUS -> 3x s_load_dwordx16
// instead of 48 scattered 4B s_load_dword (R15 diagnosis: ~1296 scalar loads
// per wave congest the scalar cache -> the ~29 us idle at full occupancy).
__global__ void transpose_w_kernel(const float* __restrict__ cw,
                                   float* __restrict__ wt) {
    const int i = blockIdx.x * 256 + threadIdx.x;
    if (i < OCH * 81) {
        const int c = i / 81, k = i - c * 81;
        wt[k * OCH + c] = cw[i];
    }
}

// ===== conv v8: R15 structure (direct-from-global, 1 d-slice/block, grid
// 2048, all-16-oc unroll, fp16-y pkrtz epilogue, per-block partial stats)
// with k-major weights: wv = wt[((ic*3+kd)*3+kh)*48 + kw*16 + c] — base is
// wave-uniform, kw/c compile-time, 48 consecutive floats -> s_load_dwordx16.
// Do NOT: raise min-waves (R2/R3 spill), LDS-stage x (R1-R8), MFMA im2col
// (R13), fp16 x staging (R5), grid caps/fusion (R11), tile shrink (R8).
__global__ __launch_bounds__(256, 2) void conv_stats_kernel(
    const float* __restrict__ x, const float* __restrict__ wt,
    const float* __restrict__ cb, const float* __restrict__ mult,
    unsigned short* __restrict__ y, float* __restrict__ stats)
{
    __shared__ float wsum[4][OCH], wsq[4][OCH];

    const int blk = blockIdx.x;
    const int b = blk >> 4;
    const int d = blk & 15;
    const int tid = threadIdx.x;

    const int h  = tid >> 3;        // 0..31
    const int wq = (tid & 7) << 2;  // 0,4,...,28

    float acc[OCH][4];
#pragma unroll
    for (int c = 0; c < OCH; c++) {
        const float bv = cb[c];
        acc[c][0] = bv; acc[c][1] = bv; acc[c][2] = bv; acc[c][3] = bv;
    }

    for (int ic = 0; ic < ICH; ic++) {
        for (int kd = 0; kd < 3; kd++) {
            const float* plane = x + ((size_t)(b * ICH + ic) * ID + (d + kd)) * (IH * IW);
            const float* wgrp  = wt + (ic * 3 + kd) * 3 * 48;   // 3 kh x 48 floats
#pragma unroll
            for (int kh = 0; kh < 3; kh++) {
                const float* row = plane + (size_t)(h + kh) * IW + wq;
                const float4 v0 = *(const float4*)row;
                const float2 v1 = *(const float2*)(row + 4);
                float in[6];
                in[0] = v0.x; in[1] = v0.y; in[2] = v0.z; in[3] = v0.w;
                in[4] = v1.x; in[5] = v1.y;
                const float* wrow = wgrp + kh * 48;             // contiguous 48
#pragma unroll
                for (int kw = 0; kw < 3; kw++) {
#pragma unroll
                    for (int c = 0; c < OCH; c++) {
                        const float wv = wrow[kw * OCH + c];    // s_load_dwordx16 path
                        acc[c][0] = fmaf(in[kw + 0], wv, acc[c][0]);
                        acc[c][1] = fmaf(in[kw + 1], wv, acc[c][1]);
                        acc[c][2] = fmaf(in[kw + 2], wv, acc[c][2]);
                        acc[c][3] = fmaf(in[kw + 3], wv, acc[c][3]);
                    }
                }
            }
        }
    }

    // ---- multiplier fold, stats, fp16 store (v_cvt_pkrtz) ----
    float ssum[OCH], ssq[OCH];
#pragma unroll
    for (int c = 0; c < OCH; c++) {
        const float m = mult[c];
        const float o0 = acc[c][0] * m, o1 = acc[c][1] * m;
        const float o2 = acc[c][2] * m, o3 = acc[c][3] * m;
        ssum[c] = (o0 + o1) + (o2 + o3);
        ssq[c]  = (o0 * o0 + o1 * o1) + (o2 * o2 + o3 * o3);
        const size_t yi = ((size_t)(b * OCH + c) * OD + d) * (OH * OW) + h * OW + wq;
        union { fp16x2 h; unsigned int u; } p01, p23;
        p01.h = __builtin_amdgcn_cvt_pkrtz(o0, o1);
        p23.h = __builtin_amdgcn_cvt_pkrtz(o2, o3);
        uint2 pk; pk.x = p01.u; pk.y = p23.u;
        *(uint2*)&y[yi] = pk;
    }

    // ---- block reduction of stats, per-block partial write (no atomics) ----
#pragma unroll
    for (int c = 0; c < OCH; c++) {
        for (int off = 32; off > 0; off >>= 1) {
            ssum[c] += __shfl_down(ssum[c], off);
            ssq[c]  += __shfl_down(ssq[c], off);
        }
    }
    const int wave = tid >> 6, lane = tid & 63;
    if (lane == 0) {
#pragma unroll
        for (int c = 0; c < OCH; c++) { wsum[wave][c] = ssum[c]; wsq[wave][c] = ssq[c]; }
    }
    __syncthreads();
    if (tid < OCH) {
        float s = 0.0f, q = 0.0f;
#pragma unroll
        for (int k = 0; k < 4; k++) { s += wsum[k][tid]; q += wsq[k][tid]; }
        const int sbase = ((b * OD + d) * OCH + tid) * 2;
        stats[sbase + 0] = s;
        stats[sbase + 1] = q;
    }
}

// ===== norm_max (R15). Prologue sums the 16 per-d partials. 2048 blocks,
// 4 positions/thread, all 16 channel loads hoisted, fp16 decode.
__global__ __launch_bounds__(256, 2) void norm_max_kernel(
    const unsigned short* __restrict__ y, const float* __restrict__ stats,
    const float* __restrict__ mult, float* __restrict__ out)
{
    const int blk = blockIdx.x;
    const int b   = blk >> 4;
    const int seg = blk & 15;
    const int tid = threadIdx.x;

    __shared__ float srs_s[OCH], snb_s[OCH], smul_s[OCH];
    if (tid < OCH) {
        float s = 0.0f, q = 0.0f;
        for (int dd = 0; dd < OD; dd++) {
            s += stats[((b * OD + dd) * OCH + tid) * 2 + 0];
            q += stats[((b * OD + dd) * OCH + tid) * 2 + 1];
        }
        const float mean = s * (1.0f / (float)SPATIAL);
        float var = q * (1.0f / (float)SPATIAL) - mean * mean;
        var = fmaxf(var, 0.0f);
        const float rs = rsqrtf(var + EPSV);
        srs_s[tid]  = rs;
        snb_s[tid]  = -mean * rs;      // normalized = v*rs + nb
        smul_s[tid] = mult[tid];
    }
    __syncthreads();

    const int s = seg * 1024 + tid * 4;
    const unsigned short* yb = y + (size_t)b * OCH * SPATIAL + s;

    uint2 v[OCH];
#pragma unroll
    for (int c = 0; c < OCH; c++) {
        v[c] = *(const uint2*)(yb + (size_t)c * SPATIAL);
    }

    float rs[OCH], nb[OCH], mm[OCH];
#pragma unroll
    for (int c = 0; c < OCH; c++) { rs[c] = srs_s[c]; nb[c] = snb_s[c]; mm[c] = smul_s[c]; }

    float b0 = -INFINITY, b1 = -INFINITY, b2 = -INFINITY, b3 = -INFINITY;
#pragma unroll
    for (int c = 0; c < OCH; c++) {
        union { unsigned int u; __fp16 h[2]; } a0, a1;
        a0.u = v[c].x; a1.u = v[c].y;
        float f0 = (float)a0.h[0] * rs[c] + nb[c];
        float f1 = (float)a0.h[1] * rs[c] + nb[c];
        float f2 = (float)a1.h[0] * rs[c] + nb[c];
        float f3 = (float)a1.h[1] * rs[c] + nb[c];
        f0 = fminf(fmaxf(f0, -1.0f), 1.0f) * mm[c];
        f1 = fminf(fmaxf(f1, -1.0f), 1.0f) * mm[c];
        f2 = fminf(fmaxf(f2, -1.0f), 1.0f) * mm[c];
        f3 = fminf(fmaxf(f3, -1.0f), 1.0f) * mm[c];
        b0 = fmaxf(b0, f0); b1 = fmaxf(b1, f1);
        b2 = fmaxf(b2, f2); b3 = fmaxf(b3, f3);
    }
    float4 o; o.x = b0; o.y = b1; o.z = b2; o.w = b3;
    *(float4*)&out[(size_t)b * SPATIAL + s] = o;
}

extern "C" void kernel_launch(void* const* d_in, const int* in_sizes, int n_in,
                              void* d_out, int out_size, void* d_ws, size_t ws_size,
                              hipStream_t stream) {
    const float* x    = (const float*)d_in[0];
    const float* cw   = (const float*)d_in[1];
    const float* cb   = (const float*)d_in[2];
    const float* mult = (const float*)d_in[3];
    float* out = (float*)d_out;

    // ws: y (fp16, 64 MB) | stats partials (256 KB) | wt (1296 f32)
    unsigned short* y = (unsigned short*)d_ws;
    float* stats = (float*)((char*)d_ws + (size_t)NB * OCH * SPATIAL * sizeof(unsigned short));
    float* wt    = stats + NB * OD * OCH * 2;

    transpose_w_kernel<<<6, 256, 0, stream>>>(cw, wt);
    conv_stats_kernel<<<NB * 16, 256, 0, stream>>>(x, wt, cb, mult, y, stats);
    norm_max_kernel<<<NB * 16, 256, 0, stream>>>(y, stats, mult, out);
}